// Round 1
// baseline (769.849 us; speedup 1.0000x reference)
//
#include <hip/hip_runtime.h>
#include <float.h>

// SOM2D: for each of N samples find argmin_m ||x_n - w_m||^2, emit grid[m] (int2).
// N=32768, M=4096, D=128. fp32, compute-bound on the vector ALU (no fp32 MFMA).

constexpr int D  = 128;
constexpr int BS = 64;   // samples per block
constexpr int BU = 64;   // units per tile
constexpr int C4 = D / 4;  // 32 float4 chunks per row

// ||w||^2 per unit -> d_ws
__global__ void wsq_kernel(const float* __restrict__ w, float* __restrict__ wsq, int M) {
    int u = blockIdx.x * blockDim.x + threadIdx.x;
    if (u >= M) return;
    const float4* wp = reinterpret_cast<const float4*>(w + (size_t)u * D);
    float s = 0.f;
#pragma unroll
    for (int k = 0; k < C4; ++k) {
        float4 v = wp[k];
        s = fmaf(v.x, v.x, s); s = fmaf(v.y, v.y, s);
        s = fmaf(v.z, v.z, s); s = fmaf(v.w, v.w, s);
    }
    wsq[u] = s;
}

// LDS layout: xs/ws are [64][128] fp32, XOR-swizzled at float4-chunk granularity:
// chunk c of row r lives at chunk (c ^ (r & 7)). Row stride 512 B (= full bank
// rotation) would otherwise put every row on bank-quad 0 -> 16-way conflicts on
// the W fragment reads. With the swizzle: x reads conflict-free, w reads 2-way
// (free, m136), staging stores conflict-free. Total LDS = exactly 64 KB ->
// 2 blocks/CU (128 KB of 160 KB).
__global__ __launch_bounds__(256) void som_kernel(
        const float* __restrict__ x, const float* __restrict__ w,
        const float* __restrict__ wsq, const int* __restrict__ grid,
        int* __restrict__ out, int M) {
    __shared__ float xs[BS * D];
    __shared__ float ws[BU * D];

    const int t  = threadIdx.x;
    const int tx = t & 15;   // unit-lane: units tx + 16*j
    const int ty = t >> 4;   // sample-lane: samples ty + 16*i
    const int sBase = blockIdx.x * BS;

    // ---- stage X tile (coalesced: flat float4 index == global float4 index) ----
    {
        const float4* xg = reinterpret_cast<const float4*>(x + (size_t)sBase * D);
#pragma unroll
        for (int k = 0; k < 8; ++k) {
            int f   = t + 256 * k;       // 0..2047
            int row = f >> 5;
            int c   = f & 31;
            float4 v = xg[f];
            int sc = c ^ (row & 7);      // swizzled chunk
            *reinterpret_cast<float4*>(&xs[row * D + sc * 4]) = v;
        }
    }
    __syncthreads();

    // ---- per-sample ||x||^2 (order-permuted sum; fp32, matches scale of ref) ----
    float xq[4];
#pragma unroll
    for (int i = 0; i < 4; ++i) {
        const float4* xr = reinterpret_cast<const float4*>(&xs[(ty + 16 * i) * D]);
        float s = 0.f;
#pragma unroll
        for (int k = 0; k < C4; ++k) {
            float4 v = xr[k];
            s = fmaf(v.x, v.x, s); s = fmaf(v.y, v.y, s);
            s = fmaf(v.z, v.z, s); s = fmaf(v.w, v.w, s);
        }
        xq[i] = s;
    }

    // byte-address bases with the (row&7) xor baked in: addr = base ^ (d4<<4)
    int xbase[4], wbase[4];
#pragma unroll
    for (int i = 0; i < 4; ++i) {
        int r = ty + 16 * i;
        xbase[i] = r * (D * 4) + ((r & 7) << 4);
    }

    float bestD[4];
    int   bestI[4];
#pragma unroll
    for (int i = 0; i < 4; ++i) { bestD[i] = FLT_MAX; bestI[i] = 0; }

    const char* xsb = reinterpret_cast<const char*>(xs);
    const char* wsb = reinterpret_cast<const char*>(ws);

    const int numTiles = M / BU;
    for (int ut = 0; ut < numTiles; ++ut) {
        const int uBase = ut * BU;
        __syncthreads();  // previous tile's readers done with ws
        {
            const float4* wg = reinterpret_cast<const float4*>(w + (size_t)uBase * D);
#pragma unroll
            for (int k = 0; k < 8; ++k) {
                int f   = t + 256 * k;
                int row = f >> 5;
                int c   = f & 31;
                float4 v = wg[f];
                int sc = c ^ (row & 7);
                *reinterpret_cast<float4*>(&ws[row * D + sc * 4]) = v;
            }
        }
        __syncthreads();

#pragma unroll
        for (int j = 0; j < 4; ++j) {
            int r = tx + 16 * j;
            wbase[j] = r * (D * 4) + ((r & 7) << 4);
        }

        float acc[4][4];
#pragma unroll
        for (int i = 0; i < 4; ++i)
#pragma unroll
            for (int j = 0; j < 4; ++j) acc[i][j] = 0.f;

#pragma unroll
        for (int d4 = 0; d4 < C4; ++d4) {
            const int xmask = d4 << 4;   // compile-time after unroll
            float4 xv[4], wv[4];
#pragma unroll
            for (int i = 0; i < 4; ++i)
                xv[i] = *reinterpret_cast<const float4*>(xsb + (xbase[i] ^ xmask));
#pragma unroll
            for (int j = 0; j < 4; ++j)
                wv[j] = *reinterpret_cast<const float4*>(wsb + (wbase[j] ^ xmask));
#pragma unroll
            for (int i = 0; i < 4; ++i)
#pragma unroll
                for (int j = 0; j < 4; ++j) {
                    acc[i][j] = fmaf(xv[i].x, wv[j].x, acc[i][j]);
                    acc[i][j] = fmaf(xv[i].y, wv[j].y, acc[i][j]);
                    acc[i][j] = fmaf(xv[i].z, wv[j].z, acc[i][j]);
                    acc[i][j] = fmaf(xv[i].w, wv[j].w, acc[i][j]);
                }
        }

        // score = (||x||^2 + ||w||^2) - 2*cross  (same association as reference)
#pragma unroll
        for (int j = 0; j < 4; ++j) {
            const int u = uBase + tx + 16 * j;   // ascending across j and tiles
            const float wq = wsq[u];
#pragma unroll
            for (int i = 0; i < 4; ++i) {
                float score = (xq[i] + wq) - 2.f * acc[i][j];
                if (score < bestD[i]) { bestD[i] = score; bestI[i] = u; }  // strict <: keeps lowest idx
            }
        }
    }

    // ---- cross-thread reduction: 16 unit-lanes per sample ----
    __syncthreads();  // everyone done reading xs/ws
    float* base = &xs[0];
    float (*redD)[17] = reinterpret_cast<float(*)[17]>(base);            // 64x17 floats
    int   (*redI)[17] = reinterpret_cast<int  (*)[17]>(base + 64 * 17);  // 64x17 ints
#pragma unroll
    for (int i = 0; i < 4; ++i) {
        redD[ty + 16 * i][tx] = bestD[i];
        redI[ty + 16 * i][tx] = bestI[i];
    }
    __syncthreads();
    if (t < BS) {
        float bd = redD[t][0];
        int   bi = redI[t][0];
#pragma unroll
        for (int k = 1; k < 16; ++k) {
            float dk = redD[t][k];
            int   ik = redI[t][k];
            if (dk < bd || (dk == bd && ik < bi)) { bd = dk; bi = ik; }
        }
        const int s = sBase + t;
        out[2 * s]     = grid[2 * bi];
        out[2 * s + 1] = grid[2 * bi + 1];
    }
}

extern "C" void kernel_launch(void* const* d_in, const int* in_sizes, int n_in,
                              void* d_out, int out_size, void* d_ws, size_t ws_size,
                              hipStream_t stream) {
    const float* x    = (const float*)d_in[0];
    const float* w    = (const float*)d_in[1];
    const int*   grid = (const int*)d_in[2];
    int* out = (int*)d_out;

    const int N = in_sizes[0] / D;   // 32768
    const int M = in_sizes[1] / D;   // 4096
    float* wsq = (float*)d_ws;       // M floats of scratch

    wsq_kernel<<<(M + 255) / 256, 256, 0, stream>>>(w, wsq, M);
    som_kernel<<<N / BS, 256, 0, stream>>>(x, w, wsq, grid, out, M);
}